// Round 1
// 117.546 us; speedup vs baseline: 1.0720x; 1.0720x over previous
//
#include <hip/hip_runtime.h>

#define NORM_EPS 1e-12f

#if defined(__has_builtin) && __has_builtin(__builtin_amdgcn_sdot4)
__device__ __forceinline__ int sdot4(unsigned a, unsigned b, int c) {
    return __builtin_amdgcn_sdot4((int)a, (int)b, c, false);
}
#else
__device__ __forceinline__ int sdot4(unsigned a, unsigned b, int c) {
    #pragma unroll
    for (int i = 0; i < 4; ++i)
        c += (int)(signed char)(a >> (8 * i)) * (int)(signed char)(b >> (8 * i));
    return c;
}
#endif

// Kernel 1: per row — L2-normalize, fold sqrt(|d|) into the row, quantize to
// int8 with per-row absmax scale. Two rows per wave (32 lanes/row), float4
// (16B/lane) loads, 5-deep 32-lane reductions, packed 4xint8 uint stores.
// Table layout unchanged: row-major 128 B/row.
__global__ __launch_bounds__(256) void build_tables_kernel(
        const float* __restrict__ emb,
        const float* __restrict__ dvec,
        unsigned* __restrict__ tblE,   // row*32 + r  (uint words)
        unsigned* __restrict__ tblW,
        float* __restrict__ scl,
        int* __restrict__ flag,
        int n_nodes) {
    int wid  = (blockIdx.x * blockDim.x + threadIdx.x) >> 6;
    int lane = threadIdx.x & 63;
    int r    = lane & 31;              // position within row (float4 granules)
    int row  = wid * 2 + (lane >> 5);  // 2 rows per wave
    bool valid = row < n_nodes;
    int crow = valid ? row : (n_nodes - 1);

    float4 v = ((const float4*)(emb + (size_t)crow * 128))[r];
    float s = v.x * v.x + v.y * v.y + v.z * v.z + v.w * v.w;
    // xor offsets <32 stay within each 32-lane half (one row each)
    #pragma unroll
    for (int off = 16; off > 0; off >>= 1)
        s += __shfl_xor(s, off);
    float inv = 1.0f / fmaxf(sqrtf(s), NORM_EPS);

    float4 d4 = ((const float4*)dvec)[r];
    bool neg_lane = (d4.x < 0.f) || (d4.y < 0.f) || (d4.z < 0.f) || (d4.w < 0.f);
    int has_neg = (__ballot(neg_lane) != 0ull) ? 1 : 0;   // wave-uniform (d shared)

    float e0 = v.x * inv * sqrtf(fabsf(d4.x));
    float e1 = v.y * inv * sqrtf(fabsf(d4.y));
    float e2 = v.z * inv * sqrtf(fabsf(d4.z));
    float e3 = v.w * inv * sqrtf(fabsf(d4.w));

    float m = fmaxf(fmaxf(fabsf(e0), fabsf(e1)), fmaxf(fabsf(e2), fabsf(e3)));
    #pragma unroll
    for (int off = 16; off > 0; off >>= 1)
        m = fmaxf(m, __shfl_xor(m, off));

    float q = (m > 0.f) ? 127.0f / m : 0.f;
    int q0 = __float2int_rn(e0 * q), q1 = __float2int_rn(e1 * q);
    int q2 = __float2int_rn(e2 * q), q3 = __float2int_rn(e3 * q);
    unsigned pk = (unsigned)(q0 & 0xFF) | ((unsigned)(q1 & 0xFF) << 8) |
                  ((unsigned)(q2 & 0xFF) << 16) | ((unsigned)(q3 & 0xFF) << 24);
    if (valid) tblE[(size_t)crow * 32 + r] = pk;

    if (has_neg) {   // general-d path: sign-folded src-side table, shared scale
        float w0 = (d4.x < 0.f) ? -e0 : e0;
        float w1 = (d4.y < 0.f) ? -e1 : e1;
        float w2 = (d4.z < 0.f) ? -e2 : e2;
        float w3 = (d4.w < 0.f) ? -e3 : e3;
        int p0 = __float2int_rn(w0 * q), p1 = __float2int_rn(w1 * q);
        int p2 = __float2int_rn(w2 * q), p3 = __float2int_rn(w3 * q);
        unsigned pw = (unsigned)(p0 & 0xFF) | ((unsigned)(p1 & 0xFF) << 8) |
                      ((unsigned)(p2 & 0xFF) << 16) | ((unsigned)(p3 & 0xFF) << 24);
        if (valid) tblW[(size_t)crow * 32 + r] = pw;
    }
    if (valid && r == 0) {
        scl[crow] = m * (1.0f / 127.0f);
        if (crow == 0) flag[0] = has_neg;
    }
}

// Kernel 2: 8 edges per 8-lane group — one edge OWNED per lane (e == gtid).
// Coalesced index loads/stores; row indices broadcast via width-8 shfl;
// 16 independent 16B gathers in flight per lane; select-swap butterfly
// reduction leaves each lane holding its own edge's int32 total.
__global__ __launch_bounds__(256) void edge_dot_i8_kernel(
        const uint4* __restrict__ tE,
        const uint4* __restrict__ tW,
        const float* __restrict__ scl,
        const int* __restrict__ flag,
        const int* __restrict__ esrc,
        const int* __restrict__ edst,
        const float* __restrict__ scale,
        float* __restrict__ out,
        int n_edges) {
    long long gtid = (long long)blockIdx.x * blockDim.x + threadIdx.x;
    int lane8 = threadIdx.x & 7;
    long long base = gtid - lane8;          // first edge of this 8-lane group
    if (base >= n_edges) return;            // group-uniform exit (shfl-safe)
    bool valid = gtid < n_edges;
    int e = valid ? (int)gtid : (n_edges - 1);

    int s_own = esrc[e];                    // coalesced across the wave
    int t_own = edst[e];
    float ss = scl[s_own] * scl[t_own];     // small array, L1/L2 resident

    const uint4* tS = (flag[0] != 0) ? tW : tE;   // d>=0 -> shared table

    int v[8];
    #pragma unroll
    for (int k = 0; k < 8; ++k) {
        int rs = __shfl(s_own, k, 8);       // broadcast edge k's rows (VALU)
        int rt = __shfl(t_own, k, 8);
        uint4 a = tS[(size_t)rs * 8 + lane8];   // 128B row, 8 lanes x 16B
        uint4 b = tE[(size_t)rt * 8 + lane8];
        int acc = 0;
        acc = sdot4(a.x, b.x, acc); acc = sdot4(a.y, b.y, acc);
        acc = sdot4(a.z, b.z, acc); acc = sdot4(a.w, b.w, acc);
        v[k] = acc;
    }

    // Select-swap butterfly: after 3 levels lane l holds the full sum for
    // edge (base + l). 7 shuffles for 8 edges.
    int k0, s0;
    k0 = (lane8 & 1) ? v[1] : v[0];  s0 = (lane8 & 1) ? v[0] : v[1];
    int w0 = k0 + __shfl_xor(s0, 1);
    k0 = (lane8 & 1) ? v[3] : v[2];  s0 = (lane8 & 1) ? v[2] : v[3];
    int w1 = k0 + __shfl_xor(s0, 1);
    k0 = (lane8 & 1) ? v[5] : v[4];  s0 = (lane8 & 1) ? v[4] : v[5];
    int w2 = k0 + __shfl_xor(s0, 1);
    k0 = (lane8 & 1) ? v[7] : v[6];  s0 = (lane8 & 1) ? v[6] : v[7];
    int w3 = k0 + __shfl_xor(s0, 1);

    k0 = (lane8 & 2) ? w1 : w0;  s0 = (lane8 & 2) ? w0 : w1;
    int u0 = k0 + __shfl_xor(s0, 2);
    k0 = (lane8 & 2) ? w3 : w2;  s0 = (lane8 & 2) ? w2 : w3;
    int u1 = k0 + __shfl_xor(s0, 2);

    k0 = (lane8 & 4) ? u1 : u0;  s0 = (lane8 & 4) ? u0 : u1;
    int tot = k0 + __shfl_xor(s0, 4);

    if (valid) out[gtid] = (float)tot * ss * scale[0];   // coalesced store
}

extern "C" void kernel_launch(void* const* d_in, const int* in_sizes, int n_in,
                              void* d_out, int out_size, void* d_ws, size_t ws_size,
                              hipStream_t stream) {
    const float* emb   = (const float*)d_in[0];
    const int*   esrc  = (const int*)d_in[1];
    const int*   edst  = (const int*)d_in[2];
    const float* dvec  = (const float*)d_in[3];
    const float* scale = (const float*)d_in[4];
    float*       out   = (float*)d_out;

    int n_nodes = in_sizes[0] / 128;
    int n_edges = in_sizes[1];

    // workspace layout (16B-aligned for n_nodes=100000)
    char* base = (char*)d_ws;
    size_t tbl_bytes = (size_t)n_nodes * 128;
    unsigned* tblE = (unsigned*)base;
    unsigned* tblW = (unsigned*)(base + tbl_bytes);
    float*    scl  = (float*)(base + 2 * tbl_bytes);
    int*      flag = (int*)(base + 2 * tbl_bytes + (size_t)n_nodes * 4);

    {   // 2 rows per wave, 8 rows per 256-thread block
        int waves  = (n_nodes + 1) / 2;
        int blocks = (waves + 3) / 4;
        build_tables_kernel<<<blocks, 256, 0, stream>>>(
            emb, dvec, tblE, tblW, scl, flag, n_nodes);
    }
    {   // 8 edges per 8-lane group -> 1 edge per thread
        long long threads = ((long long)n_edges + 7) / 8 * 8;
        int blocks = (int)((threads + 255) / 256);
        edge_dot_i8_kernel<<<blocks, 256, 0, stream>>>(
            (const uint4*)tblE, (const uint4*)tblW, scl, flag,
            esrc, edst, scale, out, n_edges);
    }
}

// Round 2
// 114.748 us; speedup vs baseline: 1.0981x; 1.0244x over previous
//
#include <hip/hip_runtime.h>

#define NORM_EPS 1e-12f

#if defined(__has_builtin) && __has_builtin(__builtin_amdgcn_sdot4)
__device__ __forceinline__ int sdot4(unsigned a, unsigned b, int c) {
    return __builtin_amdgcn_sdot4((int)a, (int)b, c, false);
}
#else
__device__ __forceinline__ int sdot4(unsigned a, unsigned b, int c) {
    #pragma unroll
    for (int i = 0; i < 4; ++i)
        c += (int)(signed char)(a >> (8 * i)) * (int)(signed char)(b >> (8 * i));
    return c;
}
#endif

// Kernel 1: per row — L2-normalize, fold sqrt(|d|) into the row, quantize to
// int8 with per-row absmax scale. 8 lanes per row: each lane owns 16
// contiguous elements (4 x float4 at 128B stride, so each load instruction
// reads one full cacheline per 8-lane group). Reductions: 16 in-lane FMAs +
// 3 shuffles (vs 10 shuffles at 32 lanes/row). 32 rows per 256-thread block.
__global__ __launch_bounds__(256) void build_tables_kernel(
        const float* __restrict__ emb,
        const float* __restrict__ dvec,
        unsigned* __restrict__ tblE,   // row*32 + word  (uint words)
        unsigned* __restrict__ tblW,
        float* __restrict__ scl,
        int* __restrict__ flag,
        int n_nodes) {
    int tid = blockIdx.x * blockDim.x + threadIdx.x;
    int row = tid >> 3;
    int l8  = threadIdx.x & 7;
    bool valid = row < n_nodes;
    int crow = valid ? row : (n_nodes - 1);

    const float4* prow = (const float4*)(emb + (size_t)crow * 128);
    const float4* pd   = (const float4*)dvec;

    float4 v[4], dd[4];
    #pragma unroll
    for (int j = 0; j < 4; ++j) {       // granule l8+8j -> cacheline j of row
        v[j]  = prow[l8 + 8 * j];
        dd[j] = pd[l8 + 8 * j];
    }

    float s = 0.f;
    #pragma unroll
    for (int j = 0; j < 4; ++j)
        s += v[j].x * v[j].x + v[j].y * v[j].y + v[j].z * v[j].z + v[j].w * v[j].w;
    s += __shfl_xor(s, 1); s += __shfl_xor(s, 2); s += __shfl_xor(s, 4);
    float inv = 1.0f / fmaxf(sqrtf(s), NORM_EPS);

    bool neg_lane = false;
    #pragma unroll
    for (int j = 0; j < 4; ++j)
        neg_lane |= (dd[j].x < 0.f) | (dd[j].y < 0.f) | (dd[j].z < 0.f) | (dd[j].w < 0.f);
    int has_neg = (__ballot(neg_lane) != 0ull) ? 1 : 0;   // d shared by all rows

    float4 e[4];
    #pragma unroll
    for (int j = 0; j < 4; ++j) {
        e[j].x = v[j].x * inv * sqrtf(fabsf(dd[j].x));
        e[j].y = v[j].y * inv * sqrtf(fabsf(dd[j].y));
        e[j].z = v[j].z * inv * sqrtf(fabsf(dd[j].z));
        e[j].w = v[j].w * inv * sqrtf(fabsf(dd[j].w));
    }

    float m = 0.f;
    #pragma unroll
    for (int j = 0; j < 4; ++j)
        m = fmaxf(m, fmaxf(fmaxf(fabsf(e[j].x), fabsf(e[j].y)),
                           fmaxf(fabsf(e[j].z), fabsf(e[j].w))));
    m = fmaxf(m, __shfl_xor(m, 1));
    m = fmaxf(m, __shfl_xor(m, 2));
    m = fmaxf(m, __shfl_xor(m, 4));

    float q = (m > 0.f) ? 127.0f / m : 0.f;
    size_t wbase = (size_t)crow * 32 + l8;
    if (valid) {
        #pragma unroll
        for (int j = 0; j < 4; ++j) {   // word l8+8j: 8 lanes -> 32B contiguous
            int q0 = __float2int_rn(e[j].x * q), q1 = __float2int_rn(e[j].y * q);
            int q2 = __float2int_rn(e[j].z * q), q3 = __float2int_rn(e[j].w * q);
            tblE[wbase + 8 * j] = (unsigned)(q0 & 0xFF) | ((unsigned)(q1 & 0xFF) << 8) |
                                  ((unsigned)(q2 & 0xFF) << 16) | ((unsigned)(q3 & 0xFF) << 24);
        }
    }
    if (has_neg && valid) {   // general-d path: sign-folded src table, shared scale
        #pragma unroll
        for (int j = 0; j < 4; ++j) {
            float w0 = (dd[j].x < 0.f) ? -e[j].x : e[j].x;
            float w1 = (dd[j].y < 0.f) ? -e[j].y : e[j].y;
            float w2 = (dd[j].z < 0.f) ? -e[j].z : e[j].z;
            float w3 = (dd[j].w < 0.f) ? -e[j].w : e[j].w;
            int p0 = __float2int_rn(w0 * q), p1 = __float2int_rn(w1 * q);
            int p2 = __float2int_rn(w2 * q), p3 = __float2int_rn(w3 * q);
            tblW[wbase + 8 * j] = (unsigned)(p0 & 0xFF) | ((unsigned)(p1 & 0xFF) << 8) |
                                  ((unsigned)(p2 & 0xFF) << 16) | ((unsigned)(p3 & 0xFF) << 24);
        }
    }
    if (valid && l8 == 0) {
        scl[crow] = m * (1.0f / 127.0f);
        if (crow == 0) flag[0] = has_neg;
    }
}

// Kernel 2: 8 edges per 8-lane group — one edge OWNED per lane (e == gtid).
// Coalesced index loads/stores; row indices broadcast via width-8 shfl;
// 16 independent 16B gathers in flight per lane, addressed as SGPR-base +
// 32-bit voffset (table is 12.8MB, offsets provably fit u32); select-swap
// butterfly leaves each lane holding its own edge's int32 total.
__global__ __launch_bounds__(256) void edge_dot_i8_kernel(
        const uint4* __restrict__ tE,
        const uint4* __restrict__ tW,
        const float* __restrict__ scl,
        const int* __restrict__ flag,
        const int* __restrict__ esrc,
        const int* __restrict__ edst,
        const float* __restrict__ scale,
        float* __restrict__ out,
        int n_edges) {
    long long gtid = (long long)blockIdx.x * blockDim.x + threadIdx.x;
    int lane8 = threadIdx.x & 7;
    long long base = gtid - lane8;          // first edge of this 8-lane group
    if (base >= n_edges) return;            // group-uniform exit (shfl-safe)
    bool valid = gtid < n_edges;
    int e = valid ? (int)gtid : (n_edges - 1);

    float sc = scale[0];                    // uniform -> s_load
    int s_own = esrc[e];                    // coalesced across the wave
    int t_own = edst[e];
    float ss = scl[(unsigned)s_own] * scl[(unsigned)t_own];

    const uint4* tS = (flag[0] != 0) ? tW : tE;   // d>=0 -> shared table

    int v[8];
    #pragma unroll
    for (int k = 0; k < 8; ++k) {
        int rs = __shfl(s_own, k, 8);       // broadcast edge k's rows (VALU)
        int rt = __shfl(t_own, k, 8);
        unsigned offa = (unsigned)rs * 8u + (unsigned)lane8;  // u32 voffset
        unsigned offb = (unsigned)rt * 8u + (unsigned)lane8;
        uint4 a = tS[offa];                 // 128B row, 8 lanes x 16B
        uint4 b = tE[offb];
        int acc = 0;
        acc = sdot4(a.x, b.x, acc); acc = sdot4(a.y, b.y, acc);
        acc = sdot4(a.z, b.z, acc); acc = sdot4(a.w, b.w, acc);
        v[k] = acc;
    }

    // Select-swap butterfly: after 3 levels lane l holds the full sum for
    // edge (base + l). 7 shuffles for 8 edges.
    int k0, s0;
    k0 = (lane8 & 1) ? v[1] : v[0];  s0 = (lane8 & 1) ? v[0] : v[1];
    int w0 = k0 + __shfl_xor(s0, 1);
    k0 = (lane8 & 1) ? v[3] : v[2];  s0 = (lane8 & 1) ? v[2] : v[3];
    int w1 = k0 + __shfl_xor(s0, 1);
    k0 = (lane8 & 1) ? v[5] : v[4];  s0 = (lane8 & 1) ? v[4] : v[5];
    int w2 = k0 + __shfl_xor(s0, 1);
    k0 = (lane8 & 1) ? v[7] : v[6];  s0 = (lane8 & 1) ? v[6] : v[7];
    int w3 = k0 + __shfl_xor(s0, 1);

    k0 = (lane8 & 2) ? w1 : w0;  s0 = (lane8 & 2) ? w0 : w1;
    int u0 = k0 + __shfl_xor(s0, 2);
    k0 = (lane8 & 2) ? w3 : w2;  s0 = (lane8 & 2) ? w2 : w3;
    int u1 = k0 + __shfl_xor(s0, 2);

    k0 = (lane8 & 4) ? u1 : u0;  s0 = (lane8 & 4) ? u0 : u1;
    int tot = k0 + __shfl_xor(s0, 4);

    if (valid) out[gtid] = (float)tot * ss * sc;   // coalesced store
}

extern "C" void kernel_launch(void* const* d_in, const int* in_sizes, int n_in,
                              void* d_out, int out_size, void* d_ws, size_t ws_size,
                              hipStream_t stream) {
    const float* emb   = (const float*)d_in[0];
    const int*   esrc  = (const int*)d_in[1];
    const int*   edst  = (const int*)d_in[2];
    const float* dvec  = (const float*)d_in[3];
    const float* scale = (const float*)d_in[4];
    float*       out   = (float*)d_out;

    int n_nodes = in_sizes[0] / 128;
    int n_edges = in_sizes[1];

    // workspace layout (16B-aligned for n_nodes=100000)
    char* base = (char*)d_ws;
    size_t tbl_bytes = (size_t)n_nodes * 128;
    unsigned* tblE = (unsigned*)base;
    unsigned* tblW = (unsigned*)(base + tbl_bytes);
    float*    scl  = (float*)(base + 2 * tbl_bytes);
    int*      flag = (int*)(base + 2 * tbl_bytes + (size_t)n_nodes * 4);

    {   // 8 lanes per row, 32 rows per 256-thread block
        long long threads = (long long)n_nodes * 8;
        int blocks = (int)((threads + 255) / 256);
        build_tables_kernel<<<blocks, 256, 0, stream>>>(
            emb, dvec, tblE, tblW, scl, flag, n_nodes);
    }
    {   // 8 edges per 8-lane group -> 1 edge per thread
        long long threads = ((long long)n_edges + 7) / 8 * 8;
        int blocks = (int)((threads + 255) / 256);
        edge_dot_i8_kernel<<<blocks, 256, 0, stream>>>(
            (const uint4*)tblE, (const uint4*)tblW, scl, flag,
            esrc, edst, scale, out, n_edges);
    }
}